// Round 10
// baseline (428.212 us; speedup 1.0000x reference)
//
#include <hip/hip_runtime.h>
#include <hip/hip_bf16.h>

// ---------------- sizes ----------------
// B=8, C=64, H=W=96, S=9216, NH=4 (dil=1,2,4,8), NL=8, hid=16
// KV rows per (i,b): 256 (0..127 = K via k_w, 128..255 = V via v_w)
// conv GEMM per (i,b): [256 o] x [576 k = tap*64+c] x [9216 s], LDS-free

// ---------------- workspace layout (bytes) ----------------
#define WS_CEN    0UL           // bf16 cenT [8][112][112][64] = 12,845,056 (channel-last, halo)
#define WS_W      25690112UL    // bf16 [4][18][256][32]      =  1,179,648 (frag-ready)
#define WS_Q      28049408UL    // bf16 [8][64][9216]         =  9,437,184 (row = o*4+i)
#define WS_KV     46923776UL    // bf16 [4][8][256][9216]     = 150,994,944
#define WS_SPART  197918720UL   // f32 [576][2048]            =  4,718,592
#define WS_KKP    202637312UL   // f32 [576][128]             =    294,912
#define WS_QQP    202932224UL   // f32 [576][16]              =     36,864
#define WS_ATTN   202969088UL   // f32 [32][128][16]          =    262,144
#define WS_AB     203231232UL   // bf16 [8][16][64][32]       =    524,288 (folded ow@attn)
#define WS_BNP    203755520UL   // f32 [576][128] per-block BN partials
#define WS_BNF    204050432UL   // f32 [128] combined sums

typedef __attribute__((ext_vector_type(8))) short short8;
typedef __attribute__((ext_vector_type(4))) float f32x4;

__device__ __forceinline__ float bflo(unsigned int u){ return __uint_as_float(u<<16); }
__device__ __forceinline__ float bfhi(unsigned int u){ return __uint_as_float(u & 0xffff0000u); }
__device__ __forceinline__ unsigned short f2bf(float f){
  unsigned int u = __float_as_uint(f);
  return (unsigned short)((u + 0x7fffu + ((u>>16)&1u)) >> 16);
}
__device__ __forceinline__ unsigned short fbits(float f){
  __hip_bfloat16 h = __float2bfloat16(f);
  return __builtin_bit_cast(unsigned short, h);
}

// ---- padT: cen [8,64,96,96] f32 -> cenT [8,112,112,64] bf16 channel-last.
// Halo zeroed by hipMemsetAsync before launch; this writes interior only.
__global__ __launch_bounds__(256) void padT_kernel(const float* __restrict__ cen,
    unsigned short* __restrict__ cenT){
  __shared__ float T[64][97];
  int y = blockIdx.x, b = blockIdx.y;
  int tid = threadIdx.x;
  const float* src = cen + (size_t)b*64*9216 + y*96;
  #pragma unroll
  for (int ch = 0; ch < 24; ++ch) {
    int idx = ch*256 + tid;
    int c = idx / 96, x = idx - c*96;
    T[c][x] = src[(size_t)c*9216 + x];
  }
  __syncthreads();
  unsigned short* dst = cenT + (((size_t)b*112 + y + 8)*112 + 8)*64;
  #pragma unroll
  for (int ch = 0; ch < 24; ++ch) {
    int idx = ch*256 + tid;
    int x = idx >> 6, c = idx & 63;
    dst[(size_t)x*64 + c] = fbits(T[c][x]);
  }
}

// ---- prep: conv weights bf16, frag-ready (R7 layout):
// Wb[((i*18 + kc)*256 + o)*32 + k'] where k = t*64 + c, kc=k>>5, k'=k&31
__global__ __launch_bounds__(256) void prep_kernel(const float* __restrict__ sumw,
    const float* __restrict__ kw, const float* __restrict__ vw, unsigned short* __restrict__ Wb){
  int idx = blockIdx.x*256 + threadIdx.x;  // exactly 589,824
  int o = idx & 255; int r = idx >> 8; int c = r & 63; r >>= 6; int t = r % 9; int i = r / 9;
  float l0 = sumw[(i*64 + c)*2 + 0], l1 = sumw[(i*64 + c)*2 + 1];
  float m = fmaxf(l0, l1);
  float e0 = expf(l0 - m), e1 = expf(l1 - m);
  float inv = 1.f/(e0 + e1);
  float sw0 = e0*inv, sw1 = e1*inv;
  const float* wsrc = (o < 128) ? (kw + ((size_t)i*128 + o)*512 + c)
                                : (vw + ((size_t)i*128 + (o-128))*512 + c);
  float A = 0.f;
  #pragma unroll
  for (int j = 0; j < 8; ++j) A += wsrc[j*64];
  float val;
  if (t == 4) {
    val = A;  // center tap: all mixed kernels weight 1 at center (sw0+sw1=1)
  } else {
    const int tmap[9] = {0,1,2,7,0,3,6,5,4};
    int j = tmap[t];
    val = -(wsrc[j*64]*sw0 + A*sw1*0.125f);
  }
  int k = t*64 + c;
  Wb[(((size_t)i*18 + (k>>5))*256 + o)*32 + (k&31)] = f2bf(val);
}

// ---- Q projection: read cen ONCE, all 4 shifts x 16 rows -> Q bf16
__global__ __launch_bounds__(256) void qproj_kernel(const float* __restrict__ cen,
    const float* __restrict__ qw, unsigned short* __restrict__ qbf){
  __shared__ float WT[64][64];  // [c][row]
  int tid = threadIdx.x;
  int st = blockIdx.x, b = blockIdx.y;
  #pragma unroll
  for (int e = 0; e < 16; ++e) {
    int f = e*256 + tid; int c = f >> 6, row = f & 63;
    int i = row & 3, o = row >> 2;
    WT[c][row] = qw[(size_t)i*1024 + o*64 + c];
  }
  __syncthreads();
  int s = st*256 + tid;
  float acc[64];
  #pragma unroll
  for (int r = 0; r < 64; ++r) acc[r] = 0.f;
  const float* cb = cen + (size_t)b*64*9216 + s;
  for (int c = 0; c < 64; ++c) {
    float xv = cb[(size_t)c*9216];
    #pragma unroll
    for (int r4 = 0; r4 < 16; ++r4) {
      float4 w = *(const float4*)&WT[c][r4*4];
      acc[r4*4+0] = fmaf(w.x, xv, acc[r4*4+0]);
      acc[r4*4+1] = fmaf(w.y, xv, acc[r4*4+1]);
      acc[r4*4+2] = fmaf(w.z, xv, acc[r4*4+2]);
      acc[r4*4+3] = fmaf(w.w, xv, acc[r4*4+3]);
    }
  }
  unsigned short* qb = qbf + (size_t)b*64*9216 + s;
  #pragma unroll
  for (int r = 0; r < 64; ++r) qb[(size_t)r*9216] = fbits(acc[r]);
}

// ---- conv K/V via MFMA, LDS-FREE: channel-last cenT makes the B fragment a
// direct global short8 load (wave's 64 lanes tile a contiguous 2KB region).
// No barriers, no staging — pure loads->MFMA dataflow, compiler-pipelined.
// Block 256thr = 4 waves (2 wm x 2 wn); tile O=128 x S=256; per-wave 64x128.
__global__ __launch_bounds__(256, 2) void conv_kv_mfma(const unsigned short* __restrict__ cenT,
    const unsigned short* __restrict__ Wb, unsigned short* __restrict__ KV){
  const int tid = threadIdx.x;
  const int st = blockIdx.x, oc = blockIdx.y, ib = blockIdx.z;
  const int i = ib >> 3, b = ib & 7;
  const int dil = 1 << i;
  const int s0 = st*256;
  const int wave = tid >> 6, lane = tid & 63;
  const int wm = wave >> 1, wn = wave & 1;
  const int l15 = lane & 15, l4 = lane >> 4;

  // per-lane spatial byte-element offsets for the 8 nf column groups
  int offs[8];
  #pragma unroll
  for (int nf = 0; nf < 8; ++nf) {
    int s = s0 + wn*128 + nf*16 + l15;
    int y = s / 96, x = s - y*96;
    offs[nf] = ((y+8)*112 + (x+8))*64 + l4*8;
  }
  const unsigned short* cb = cenT + (size_t)b*802816;
  const unsigned short* apb = Wb + (size_t)i*147456 + (size_t)(oc*128 + wm*64 + l15)*32 + l4*8;

  f32x4 acc[4][8];
  #pragma unroll
  for (int mf = 0; mf < 4; ++mf)
    #pragma unroll
    for (int nf = 0; nf < 8; ++nf)
      acc[mf][nf] = (f32x4){0.f, 0.f, 0.f, 0.f};

  for (int kc = 0; kc < 18; ++kc) {
    int t = kc >> 1;
    int dy = (t/3 - 1)*dil, dx = (t - (t/3)*3 - 1)*dil;
    int duni = (dy*112 + dx)*64 + (kc & 1)*32;
    short8 a[4];
    const unsigned short* ap = apb + (size_t)kc*8192;
    #pragma unroll
    for (int mf = 0; mf < 4; ++mf) a[mf] = *(const short8*)(ap + mf*512);
    short8 bf[8];
    #pragma unroll
    for (int nf = 0; nf < 8; ++nf) bf[nf] = *(const short8*)(cb + offs[nf] + duni);
    #pragma unroll
    for (int mf = 0; mf < 4; ++mf)
      #pragma unroll
      for (int nf = 0; nf < 8; ++nf)
        acc[mf][nf] = __builtin_amdgcn_mfma_f32_16x16x32_bf16(a[mf], bf[nf], acc[mf][nf], 0, 0, 0);
  }

  // epilogue: C/D mapping row=(l>>4)*4+r, col=l&15
  #pragma unroll
  for (int mf = 0; mf < 4; ++mf) {
    #pragma unroll
    for (int nf = 0; nf < 8; ++nf) {
      int scol = s0 + wn*128 + nf*16 + l15;
      int obase = oc*128 + wm*64 + mf*16 + l4*4;
      #pragma unroll
      for (int r = 0; r < 4; ++r)
        KV[((size_t)ib*256 + obase + r)*9216 + scol] = fbits(acc[mf][nf][r]);
    }
  }
}

// ---- scores via MFMA (unchanged)
__global__ __launch_bounds__(256) void scores_mfma(const unsigned short* __restrict__ KV,
    const unsigned short* __restrict__ qbf, float* __restrict__ spart,
    float* __restrict__ kkpart, float* __restrict__ qqpart){
  __shared__ float red[4][2192];
  const int tid = threadIdx.x;
  const int chunk = blockIdx.x, hh = blockIdx.y, b = blockIdx.z;
  const int wave = tid >> 6, lane = tid & 63;
  const int l15 = lane & 15, l4 = lane >> 4;
  const int sbase = chunk*512 + wave*128;

  const unsigned short* qp = qbf + ((size_t)(b*64 + hh*16 + l15))*9216 + sbase + l4*8;
  const unsigned short* kp = KV + ((size_t)(((l15&3)*8 + b)*256 + hh*32 + (l15>>2)))*9216 + sbase + l4*8;

  f32x4 sacc[8], kkacc[8], qqacc;
  #pragma unroll
  for (int nf = 0; nf < 8; ++nf) { sacc[nf] = (f32x4){0,0,0,0}; kkacc[nf] = (f32x4){0,0,0,0}; }
  qqacc = (f32x4){0,0,0,0};

  #pragma unroll
  for (int sl = 0; sl < 4; ++sl) {
    short8 qf = *(const short8*)(qp + sl*32);
    short8 kf[8];
    #pragma unroll
    for (int nf = 0; nf < 8; ++nf) kf[nf] = *(const short8*)(kp + (size_t)nf*36864 + sl*32);
    qqacc = __builtin_amdgcn_mfma_f32_16x16x32_bf16(qf, qf, qqacc, 0, 0, 0);
    #pragma unroll
    for (int nf = 0; nf < 8; ++nf) {
      sacc[nf]  = __builtin_amdgcn_mfma_f32_16x16x32_bf16(qf, kf[nf], sacc[nf], 0, 0, 0);
      kkacc[nf] = __builtin_amdgcn_mfma_f32_16x16x32_bf16(kf[nf], kf[nf], kkacc[nf], 0, 0, 0);
    }
  }
  float* rw = red[wave];
  #pragma unroll
  for (int nf = 0; nf < 8; ++nf)
    #pragma unroll
    for (int r = 0; r < 4; ++r)
      rw[(l4*4 + r)*128 + nf*16 + l15] = sacc[nf][r];
  if ((l15 >> 2) == l4) {
    int r = l15 & 3;
    #pragma unroll
    for (int nf = 0; nf < 8; ++nf) rw[2048 + nf*16 + l15] = kkacc[nf][r];
    rw[2176 + l15] = qqacc[r];
  }
  __syncthreads();
  int pb = (b*4 + hh)*18 + chunk;
  for (int t = tid; t < 2192; t += 256) {
    float v = red[0][t] + red[1][t] + red[2][t] + red[3][t];
    if (t < 2048)       spart[(size_t)pb*2048 + t] = v;
    else if (t < 2176)  kkpart[(size_t)pb*128 + (t - 2048)] = v;
    else                qqpart[(size_t)pb*16 + (t - 2176)] = v;
  }
}

// ---- softmax (unchanged)
__global__ __launch_bounds__(256) void softmax_kernel(const float* __restrict__ spart,
    const float* __restrict__ kkpart, const float* __restrict__ qqpart, float* __restrict__ attnT){
  const int pb = blockIdx.x, tid = threadIdx.x;
  const int qr = tid >> 4, g = tid & 15;
  __shared__ float kkl[128];
  __shared__ float qql[16];
  __shared__ float red[8];
  __shared__ float stats[2];
  float sv[8] = {0,0,0,0,0,0,0,0};
  for (int ch = 0; ch < 18; ++ch) {
    const float* p = spart + ((size_t)(pb*18 + ch))*2048 + qr*128 + g*8;
    #pragma unroll
    for (int e = 0; e < 8; ++e) sv[e] += p[e];
  }
  if (tid < 128) { float ssum = 0.f; for (int ch = 0; ch < 18; ++ch) ssum += kkpart[(size_t)(pb*18+ch)*128 + tid]; kkl[tid] = ssum; }
  if (tid < 16)  { float ssum = 0.f; for (int ch = 0; ch < 18; ++ch) ssum += qqpart[(size_t)(pb*18+ch)*16 + tid]; qql[tid] = ssum; }
  __syncthreads();
  float qn = fmaxf(sqrtf(qql[qr]), 1e-12f);
  float lsum = 0.f, lsq = 0.f;
  #pragma unroll
  for (int e = 0; e < 8; ++e) {
    float kn = fmaxf(sqrtf(kkl[g*8+e]), 1e-12f);
    float v = sv[e] / (qn * kn * 96.0f);
    sv[e] = v; lsum += v; lsq += v*v;
  }
  #pragma unroll
  for (int m = 1; m <= 32; m <<= 1) { lsum += __shfl_xor(lsum, m); lsq += __shfl_xor(lsq, m); }
  if ((tid & 63) == 0) { red[tid >> 6] = lsum; red[4 + (tid >> 6)] = lsq; }
  __syncthreads();
  if (tid == 0) {
    float ts = red[0]+red[1]+red[2]+red[3];
    float tq = red[4]+red[5]+red[6]+red[7];
    float mean = ts / 2048.0f;
    float var = tq / 2048.0f - mean*mean;
    stats[0] = mean; stats[1] = rsqrtf(var + 1e-5f);
  }
  __syncthreads();
  float mean = stats[0], inv = stats[1];
  float mx = -1e30f;
  #pragma unroll
  for (int e = 0; e < 8; ++e) { sv[e] = (sv[e] - mean) * inv; mx = fmaxf(mx, sv[e]); }
  #pragma unroll
  for (int m = 1; m <= 8; m <<= 1) mx = fmaxf(mx, __shfl_xor(mx, m));
  float es = 0.f;
  #pragma unroll
  for (int e = 0; e < 8; ++e) { sv[e] = expf(sv[e] - mx); es += sv[e]; }
  #pragma unroll
  for (int m = 1; m <= 8; m <<= 1) es += __shfl_xor(es, m);
  float rinv = 1.0f / es;
  #pragma unroll
  for (int e = 0; e < 8; ++e) attnT[(size_t)pb*2048 + (g*8+e)*16 + qr] = sv[e] * rinv;
}

// ---- attn fold: M[b][r][o2] = sum_qr ow[o2][hh*16+qr] * attn[b,hh][kr][qr]
__global__ __launch_bounds__(256) void attnfold_kernel(const float* __restrict__ attnT,
    const float* __restrict__ ow, unsigned short* __restrict__ Ab){
  int idx = blockIdx.x*256 + threadIdx.x;  // exactly 262,144
  int kr = idx & 127, hh = (idx >> 7) & 3, o2 = (idx >> 9) & 63, b = idx >> 15;
  const float* ap = attnT + ((size_t)(b*4 + hh))*2048 + kr*16;
  const float* wp = ow + o2*64 + hh*16;
  float acc = 0.f;
  #pragma unroll
  for (int qr = 0; qr < 16; ++qr) acc += wp[qr] * ap[qr];
  int rc = (kr & 3)*4 + hh, ch = kr >> 2;
  Ab[(((size_t)b*16 + rc)*64 + o2)*32 + ch] = fbits(acc);
}

// ---- ygemm: y[b][o2][s] = M[b] @ V[b] ([64 x 512] @ [512 x 9216]) + BN partials
__global__ __launch_bounds__(256, 3) void ygemm_kernel(const unsigned short* __restrict__ KV,
    const unsigned short* __restrict__ Ab, float* __restrict__ dout, float* __restrict__ bnpart){
  __shared__ char Xs[2][128*72];
  __shared__ float bns[4][32], bnq[4][32];
  const int tid = threadIdx.x;
  const int st = blockIdx.x, b = blockIdx.y;
  const int wave = tid >> 6, lane = tid & 63;
  const int wm = wave >> 1, wn = wave & 1;
  const int l15 = lane & 15, l4 = lane >> 4;
  const int s_idx = tid & 127, khalf = tid >> 7;
  const int s0 = st*128;

  f32x4 acc[2][4];
  #pragma unroll
  for (int mf = 0; mf < 2; ++mf)
    #pragma unroll
    for (int nf = 0; nf < 4; ++nf)
      acc[mf][nf] = (f32x4){0.f, 0.f, 0.f, 0.f};

  const unsigned short* Abb = Ab + ((size_t)b*16*64)*32 + (size_t)(wm*32 + l15)*32 + l4*8;

  unsigned short vs[16];
  auto vgather = [&](int kn){
    int vr = (((kn >> 2)*8 + b)*256 + 128 + (kn & 3)*32) + khalf*16;
    const unsigned short* p = KV + (size_t)vr*9216 + s0 + s_idx;
    #pragma unroll
    for (int j = 0; j < 16; ++j) vs[j] = p[(size_t)j*9216];
  };

  vgather(0);
  int buf = 0;
  for (int kc = 0; kc < 16; ++kc) {
    short8 a[2];
    #pragma unroll
    for (int mf = 0; mf < 2; ++mf) a[mf] = *(const short8*)(Abb + (size_t)kc*2048 + mf*512);
    asm volatile("" ::: "memory");
    char* wp = Xs[buf] + s_idx*72 + khalf*32;
    #pragma unroll
    for (int w = 0; w < 4; ++w) {
      unsigned int p0 = (unsigned int)vs[4*w+0] | ((unsigned int)vs[4*w+1] << 16);
      unsigned int p1 = (unsigned int)vs[4*w+2] | ((unsigned int)vs[4*w+3] << 16);
      *(uint2*)(wp + w*8) = make_uint2(p0, p1);
    }
    if (kc < 15) vgather(kc + 1);
    asm volatile("s_waitcnt lgkmcnt(0)" ::: "memory");
    __builtin_amdgcn_s_barrier();
    asm volatile("" ::: "memory");
    short8 bfr[4];
    #pragma unroll
    for (int nf = 0; nf < 4; ++nf) {
      const char* rp = Xs[buf] + (wn*64 + nf*16 + l15)*72 + l4*16;
      uint2 lo = *(const uint2*)rp;
      uint2 hi = *(const uint2*)(rp + 8);
      uint4 tb = make_uint4(lo.x, lo.y, hi.x, hi.y);
      bfr[nf] = *(short8*)&tb;
    }
    #pragma unroll
    for (int mf = 0; mf < 2; ++mf)
      #pragma unroll
      for (int nf = 0; nf < 4; ++nf)
        acc[mf][nf] = __builtin_amdgcn_mfma_f32_16x16x32_bf16(a[mf], bfr[nf], acc[mf][nf], 0, 0, 0);
    buf ^= 1;
  }

  #pragma unroll
  for (int mf = 0; mf < 2; ++mf) {
    #pragma unroll
    for (int rr = 0; rr < 4; ++rr) {
      int o2 = wm*32 + mf*16 + l4*4 + rr;
      float vsum = 0.f, vsq = 0.f;
      #pragma unroll
      for (int nf = 0; nf < 4; ++nf) {
        float v = acc[mf][nf][rr];
        vsum += v; vsq += v*v;
        dout[((size_t)(b*64 + o2))*9216 + s0 + wn*64 + nf*16 + l15] = v;
      }
      #pragma unroll
      for (int m = 1; m <= 8; m <<= 1) { vsum += __shfl_xor(vsum, m); vsq += __shfl_xor(vsq, m); }
      if (l15 == 0) { bns[wave][mf*16 + l4*4 + rr] = vsum; bnq[wave][mf*16 + l4*4 + rr] = vsq; }
    }
  }
  __syncthreads();
  if (tid < 64) {
    int wmq = tid >> 5, local = tid & 31;
    float s_ = bns[wmq*2][local] + bns[wmq*2+1][local];
    float q_ = bnq[wmq*2][local] + bnq[wmq*2+1][local];
    int bid = b*72 + st;
    bnpart[(size_t)bid*128 + tid] = s_;
    bnpart[(size_t)bid*128 + 64 + tid] = q_;
  }
}

// ---- combine BN partials: [576][128] -> [128] raw sums
__global__ __launch_bounds__(128) void bncombine_kernel(const float* __restrict__ bnpart, float* __restrict__ bnfin){
  int t = threadIdx.x;  // 128
  float a = 0.f;
  for (int blk = 0; blk < 576; ++blk) a += bnpart[(size_t)blk*128 + t];
  bnfin[t] = a;
}

// ---- BN apply + ReLU (in place on d_out), float4
__global__ __launch_bounds__(256) void bnapply_kernel(float* __restrict__ yb,
    const float* __restrict__ bnfin, const float* __restrict__ gamma, const float* __restrict__ beta){
  int gid = blockIdx.x*256 + threadIdx.x;  // exactly 1,179,648 float4s
  int o = (gid / 2304) & 63;
  float mean = bnfin[o] * (1.f/73728.f);
  float var = bnfin[64 + o] * (1.f/73728.f) - mean*mean;
  float inv = rsqrtf(var + 1e-5f);
  float g = gamma[o], be = beta[o];
  float4 v = ((const float4*)yb)[gid];
  v.x = fmaxf((v.x - mean)*inv*g + be, 0.f);
  v.y = fmaxf((v.y - mean)*inv*g + be, 0.f);
  v.z = fmaxf((v.z - mean)*inv*g + be, 0.f);
  v.w = fmaxf((v.w - mean)*inv*g + be, 0.f);
  ((float4*)yb)[gid] = v;
}

extern "C" void kernel_launch(void* const* d_in, const int* in_sizes, int n_in,
                              void* d_out, int out_size, void* d_ws, size_t ws_size,
                              hipStream_t stream) {
  const float* cen   = (const float*)d_in[0];
  const float* sumw  = (const float*)d_in[1];
  const float* qw    = (const float*)d_in[2];
  const float* kw    = (const float*)d_in[3];
  const float* vw    = (const float*)d_in[4];
  const float* ow    = (const float*)d_in[5];
  const float* gamma = (const float*)d_in[6];
  const float* beta  = (const float*)d_in[7];

  char* ws = (char*)d_ws;
  unsigned short* cenT   = (unsigned short*)(ws + WS_CEN);
  unsigned short* Wb     = (unsigned short*)(ws + WS_W);
  unsigned short* qbf    = (unsigned short*)(ws + WS_Q);
  unsigned short* KV     = (unsigned short*)(ws + WS_KV);
  float*          spart  = (float*)(ws + WS_SPART);
  float*          kkp    = (float*)(ws + WS_KKP);
  float*          qqp    = (float*)(ws + WS_QQP);
  float*          attnT  = (float*)(ws + WS_ATTN);
  unsigned short* Ab     = (unsigned short*)(ws + WS_AB);
  float*          bnp    = (float*)(ws + WS_BNP);
  float*          bnf    = (float*)(ws + WS_BNF);

  hipMemsetAsync(cenT, 0, 12845056UL, stream);
  padT_kernel    <<<dim3(96, 8), 256, 0, stream>>>(cen, cenT);
  prep_kernel    <<<2304, 256, 0, stream>>>(sumw, kw, vw, Wb);
  qproj_kernel   <<<dim3(36, 8), 256, 0, stream>>>(cen, qw, qbf);
  conv_kv_mfma   <<<dim3(36, 2, 32), 256, 0, stream>>>(cenT, Wb, KV);
  scores_mfma    <<<dim3(18, 4, 8), 256, 0, stream>>>(KV, qbf, spart, kkp, qqp);
  softmax_kernel <<<32, 256, 0, stream>>>(spart, kkp, qqp, attnT);
  attnfold_kernel<<<1024, 256, 0, stream>>>(attnT, ow, Ab);
  ygemm_kernel   <<<dim3(72, 8), 256, 0, stream>>>(KV, Ab, (float*)d_out, bnp);
  bncombine_kernel<<<1, 128, 0, stream>>>(bnp, bnf);
  bnapply_kernel <<<4608, 256, 0, stream>>>((float*)d_out, bnf, gamma, beta);
}